// Round 8
// baseline (57.496 us; speedup 1.0000x reference)
//
#include <hip/hip_runtime.h>

#define NDIM   16
#define MCOLS  2048
#define NANG   120           // 16*15/2
#define BLOCK  256
#define HALFC  1024          // cols per chunk = 256 threads * 4

typedef float f32x4 __attribute__((ext_vector_type(4)));

// One block per batch element b. Both 1024-col chunks processed with
// cross-chunk register prefetch so the load stream never goes empty.
__global__ __launch_bounds__(BLOCK) void soot_kernel(
    const float* __restrict__ X,
    const float* __restrict__ angles,
    const float* __restrict__ mus,
    float* __restrict__ out)
{
    __shared__ float c_lds[NANG];
    __shared__ float s_lds[NANG];
    __shared__ __align__(16) float R_lds[NDIM * NDIM];

    const int b   = blockIdx.x;
    const int tid = threadIdx.x;

    // ---- Prologue: wave 0 computes cos/sin; 16 lanes run the Givens cascade.
    if (tid < 64) {
#pragma unroll
        for (int rep = 0; rep < 2; ++rep) {
            const int k = tid + rep * 64;
            if (k < NANG) {
                float a = angles[b * NANG + k];
                float sv, cv;
                sincosf(a, &sv, &cv);
                c_lds[k] = cv;
                s_lds[k] = sv;
            }
        }
    }
    __syncthreads();

    if (tid < NDIM) {
        const int j = tid;
        float m[NDIM];
#pragma unroll
        for (int r = 0; r < NDIM; ++r) m[r] = (r == j) ? 1.0f : 0.0f;
        int k = 0;
#pragma unroll
        for (int iTop = 0; iTop < NDIM - 1; ++iTop) {
            float vt = m[iTop];
#pragma unroll
            for (int iBtm = iTop + 1; iBtm < NDIM; ++iBtm) {
                const float c  = c_lds[k];
                const float s  = s_lds[k];
                const float vb = m[iBtm];
                const float nvt = c * vt - s * vb;
                m[iBtm] = s * vt + c * vb;
                vt = nvt;
                ++k;
            }
            m[iTop] = vt;
        }
#pragma unroll
        for (int r = 0; r < NDIM; ++r)
            R_lds[r * NDIM + j] = mus[b * NDIM + r] * m[r];
    }
    __syncthreads();

    // ---- Streaming matmul with cross-chunk prefetch.
    const float* Xb = X   + (size_t)b * NDIM * MCOLS;
    float*       Ob = out + (size_t)b * NDIM * MCOLS;
    const int c0 = tid * 4;
    const int c1 = HALFC + tid * 4;

    f32x4 x0[8], x1[8], acc[NDIM];

    // chunk0: load all 16 rows.
#pragma unroll
    for (int j = 0; j < 8; ++j)
        x0[j] = *reinterpret_cast<const f32x4*>(Xb + j * MCOLS + c0);
#pragma unroll
    for (int j = 0; j < 8; ++j)
        x1[j] = *reinterpret_cast<const f32x4*>(Xb + (8 + j) * MCOLS + c0);

    // phase0 chunk0 (consume x0).
#pragma unroll
    for (int r = 0; r < NDIM; ++r) {
        acc[r] = R_lds[r * NDIM + 0] * x0[0];
#pragma unroll
        for (int q = 1; q < 8; ++q)
            acc[r] += R_lds[r * NDIM + q] * x0[q];
    }
    // prefetch chunk1 rows 0..7 into x0 (overlaps phase1 compute + stores).
#pragma unroll
    for (int j = 0; j < 8; ++j)
        x0[j] = *reinterpret_cast<const f32x4*>(Xb + j * MCOLS + c1);

    // phase1 chunk0 (consume x1).
#pragma unroll
    for (int r = 0; r < NDIM; ++r) {
#pragma unroll
        for (int q = 0; q < 8; ++q)
            acc[r] += R_lds[r * NDIM + 8 + q] * x1[q];
    }
    // prefetch chunk1 rows 8..15 into x1.
#pragma unroll
    for (int j = 0; j < 8; ++j)
        x1[j] = *reinterpret_cast<const f32x4*>(Xb + (8 + j) * MCOLS + c1);

    // store chunk0.
#pragma unroll
    for (int r = 0; r < NDIM; ++r)
        __builtin_nontemporal_store(acc[r], reinterpret_cast<f32x4*>(Ob + r * MCOLS + c0));

    // chunk1 compute (x0/x1 already in flight or arrived).
#pragma unroll
    for (int r = 0; r < NDIM; ++r) {
        acc[r] = R_lds[r * NDIM + 0] * x0[0];
#pragma unroll
        for (int q = 1; q < 8; ++q)
            acc[r] += R_lds[r * NDIM + q] * x0[q];
    }
#pragma unroll
    for (int r = 0; r < NDIM; ++r) {
#pragma unroll
        for (int q = 0; q < 8; ++q)
            acc[r] += R_lds[r * NDIM + 8 + q] * x1[q];
    }
#pragma unroll
    for (int r = 0; r < NDIM; ++r)
        __builtin_nontemporal_store(acc[r], reinterpret_cast<f32x4*>(Ob + r * MCOLS + c1));
}

extern "C" void kernel_launch(void* const* d_in, const int* in_sizes, int n_in,
                              void* d_out, int out_size, void* d_ws, size_t ws_size,
                              hipStream_t stream) {
    const float* X      = (const float*)d_in[0];
    const float* angles = (const float*)d_in[1];
    const float* mus    = (const float*)d_in[2];
    float* out          = (float*)d_out;

    const int nblks = in_sizes[1] / NANG;          // 1024
    hipLaunchKernelGGL(soot_kernel, dim3(nblks), dim3(BLOCK), 0, stream,
                       X, angles, mus, out);
}